// Round 3
// baseline (883.000 us; speedup 1.0000x reference)
//
#include <hip/hip_runtime.h>

#define B_SZ 8192
#define M_SZ 256
#define N_SZ 512
#define TB 64
#define THREADS 1024
#define LDP 520   // padded f16 row stride for state buffers
#define LDPY 264  // padded f16 row stride for y staging
#define NITER 16
#define PF 4      // matrix-fragment prefetch depth (ks steps)

typedef _Float16 half8 __attribute__((ext_vector_type(8)));
typedef _Float16 half4 __attribute__((ext_vector_type(4)));
typedef float floatx4 __attribute__((ext_vector_type(4)));

// ---- f16 conversions: W, D, D^T, S^T ----
__global__ void conv_kernel(const float* __restrict__ S, const float* __restrict__ W,
                            const float* __restrict__ D,
                            _Float16* __restrict__ Wf, _Float16* __restrict__ Df,
                            _Float16* __restrict__ Dtf, _Float16* __restrict__ Stf) {
  int i = blockIdx.x * blockDim.x + threadIdx.x;
  if (i < N_SZ * N_SZ) {
    int r = i >> 9;
    int c = i & (N_SZ - 1);
    float d = D[i];
    Df[i] = (_Float16)d;
    Dtf[c * N_SZ + r] = (_Float16)d;
    Stf[c * N_SZ + r] = (_Float16)S[i];  // St[j][k] = S[k][j]
  }
  if (i < N_SZ * M_SZ) Wf[i] = (_Float16)W[i];
}

// ---- E = D @ S via MFMA: E[i][j] = sum_k D[i][k] * St[j][k] ----
// Swapped-operand MFMA: lane holds i = lane&15, j = q*4+r -> half4 stores.
__global__ __launch_bounds__(256) void ecomp_kernel(const _Float16* __restrict__ Df,
                                                    const _Float16* __restrict__ Stf,
                                                    _Float16* __restrict__ Ef) {
  const int tid = threadIdx.x;
  const int wave = tid >> 6;
  const int lane = tid & 63;
  const int m16 = lane & 15;
  const int q = lane >> 4;
  const int i0 = (blockIdx.x & 7) * 64;                 // 8 i-groups of 64
  const int j0 = (blockIdx.x >> 3) * 128 + wave * 32;   // 4 j-groups of 128, wave picks 32

  floatx4 acc[4][2];
#pragma unroll
  for (int it = 0; it < 4; ++it) acc[it][0] = acc[it][1] = (floatx4){0.f, 0.f, 0.f, 0.f};

  const _Float16* dp = Df + (size_t)(i0 + m16) * N_SZ + q * 8;
  const _Float16* sp = Stf + (size_t)(j0 + m16) * N_SZ + q * 8;
#pragma unroll
  for (int ks = 0; ks < N_SZ / 32; ++ks) {
    half8 s0 = *reinterpret_cast<const half8*>(sp + ks * 32);
    half8 s1 = *reinterpret_cast<const half8*>(sp + 16 * N_SZ + ks * 32);
#pragma unroll
    for (int it = 0; it < 4; ++it) {
      half8 dv = *reinterpret_cast<const half8*>(dp + (size_t)it * 16 * N_SZ + ks * 32);
      acc[it][0] = __builtin_amdgcn_mfma_f32_16x16x32_f16(s0, dv, acc[it][0], 0, 0, 0);
      acc[it][1] = __builtin_amdgcn_mfma_f32_16x16x32_f16(s1, dv, acc[it][1], 0, 0, 0);
    }
  }
#pragma unroll
  for (int it = 0; it < 4; ++it)
#pragma unroll
    for (int jt = 0; jt < 2; ++jt) {
      half4 h;
#pragma unroll
      for (int r = 0; r < 4; ++r) h[r] = (_Float16)acc[it][jt][r];
      *reinterpret_cast<half4*>(Ef + (size_t)(i0 + it * 16 + m16) * N_SZ + j0 + jt * 16 + q * 4) = h;
    }
}

__global__ __launch_bounds__(THREADS, 4) void ista_kernel(
    const float* __restrict__ y, const _Float16* __restrict__ Ef,
    const _Float16* __restrict__ Df, const _Float16* __restrict__ Dtf,
    const _Float16* __restrict__ Wf, const float* __restrict__ thrp,
    float* __restrict__ out) {
  __shared__ _Float16 bufA[TB * LDP];  // d-state (initially: y staging)
  __shared__ _Float16 bufB[TB * LDP];  // s scratch (initially: Wy)

  const int tid = threadIdx.x;
  const int wave = tid >> 6;        // 0..15
  const int lane = tid & 63;
  const int m16 = lane & 15;
  const int q = lane >> 4;          // 0..3
  const int rowBase = blockIdx.x * TB;
  const int colBase = wave * 32;    // 2 n-tiles of 16 per wave

  // ---- stage y rows -> bufA (f16, stride LDPY) ----
  {
    const int r = tid >> 4;              // 0..63
    const int c0 = (tid & 15) << 4;      // 0..240
    const float* src = y + (size_t)(rowBase + r) * M_SZ + c0;
#pragma unroll
    for (int j = 0; j < 16; j += 4) {
      float4 v = *reinterpret_cast<const float4*>(src + j);
      _Float16* dst = &bufA[r * LDPY + c0 + j];
      dst[0] = (_Float16)v.x;
      dst[1] = (_Float16)v.y;
      dst[2] = (_Float16)v.z;
      dst[3] = (_Float16)v.w;
    }
  }
  __syncthreads();

  floatx4 acc[4][2];

  // ---- Wy = y @ W^T (K=256), swapped operands -> transposed tiles ----
#pragma unroll
  for (int rt = 0; rt < 4; ++rt) acc[rt][0] = acc[rt][1] = (floatx4){0.f, 0.f, 0.f, 0.f};
  {
    const _Float16* yp = bufA + m16 * LDPY + q * 8;
    const _Float16* wp0 = Wf + (size_t)(colBase + m16) * M_SZ + q * 8;
    const _Float16* wp1 = wp0 + 16 * M_SZ;
#pragma unroll
    for (int ks = 0; ks < M_SZ / 32; ++ks) {
      half8 b0 = *reinterpret_cast<const half8*>(wp0 + ks * 32);
      half8 b1 = *reinterpret_cast<const half8*>(wp1 + ks * 32);
#pragma unroll
      for (int rt = 0; rt < 4; ++rt) {
        half8 a = *reinterpret_cast<const half8*>(yp + rt * 16 * LDPY + ks * 32);
        acc[rt][0] = __builtin_amdgcn_mfma_f32_16x16x32_f16(b0, a, acc[rt][0], 0, 0, 0);
        acc[rt][1] = __builtin_amdgcn_mfma_f32_16x16x32_f16(b1, a, acc[rt][1], 0, 0, 0);
      }
    }
  }
  // write Wy -> bufB (transposed tile: lane holds row b=rt*16+m16, 4 consecutive n)
#pragma unroll
  for (int rt = 0; rt < 4; ++rt)
#pragma unroll
    for (int ct = 0; ct < 2; ++ct) {
      half4 h;
#pragma unroll
      for (int r = 0; r < 4; ++r) h[r] = (_Float16)acc[rt][ct][r];
      *reinterpret_cast<half4*>(&bufB[(rt * 16 + m16) * LDP + colBase + ct * 16 + q * 4]) = h;
    }
  __syncthreads();

  // K=512 GEMM, swapped operands, PF-deep register prefetch of matrix fragments.
  // acc[xt][nt] tile: lane holds b = xt*16+m16 (fixed), n = colBase+nt*16+q*4+r.
  auto gemmK512T = [&](const _Float16* Xbuf, const _Float16* __restrict__ Bmat) {
    const _Float16* xp = Xbuf + m16 * LDP + q * 8;
    const _Float16* bp0 = Bmat + (size_t)(colBase + m16) * N_SZ + q * 8;
    const _Float16* bp1 = bp0 + 16 * N_SZ;
    half8 mp[PF][2];
#pragma unroll
    for (int p = 0; p < PF; ++p) {
      mp[p][0] = *reinterpret_cast<const half8*>(bp0 + p * 32);
      mp[p][1] = *reinterpret_cast<const half8*>(bp1 + p * 32);
    }
#pragma unroll
    for (int ks = 0; ks < N_SZ / 32; ++ks) {
      half8 b0 = mp[ks % PF][0];
      half8 b1 = mp[ks % PF][1];
      if (ks + PF < N_SZ / 32) {
        mp[ks % PF][0] = *reinterpret_cast<const half8*>(bp0 + (ks + PF) * 32);
        mp[ks % PF][1] = *reinterpret_cast<const half8*>(bp1 + (ks + PF) * 32);
      }
#pragma unroll
      for (int xt = 0; xt < 4; ++xt) {
        half8 a = *reinterpret_cast<const half8*>(xp + xt * 16 * LDP + ks * 32);
        acc[xt][0] = __builtin_amdgcn_mfma_f32_16x16x32_f16(b0, a, acc[xt][0], 0, 0, 0);
        acc[xt][1] = __builtin_amdgcn_mfma_f32_16x16x32_f16(b1, a, acc[xt][1], 0, 0, 0);
      }
    }
  };

  // ---- c = Wy @ D^T (K=512), packed to f16 in registers ----
#pragma unroll
  for (int rt = 0; rt < 4; ++rt) acc[rt][0] = acc[rt][1] = (floatx4){0.f, 0.f, 0.f, 0.f};
  gemmK512T(bufB, Df);
  half4 ch[4][2];
#pragma unroll
  for (int rt = 0; rt < 4; ++rt)
#pragma unroll
    for (int ct = 0; ct < 2; ++ct)
#pragma unroll
      for (int r = 0; r < 4; ++r) ch[rt][ct][r] = (_Float16)acc[rt][ct][r];

  // ---- zero d state + output slice 0 ----
  {
    int* za = reinterpret_cast<int*>(bufA);
    for (int i = tid; i < TB * LDP / 2; i += THREADS) za[i] = 0;
    float4 z4 = {0.f, 0.f, 0.f, 0.f};
    float4* o4 = reinterpret_cast<float4*>(out + (size_t)rowBase * N_SZ);
    for (int i = tid; i < TB * N_SZ / 4; i += THREADS) o4[i] = z4;
  }
  __syncthreads();

  const float thrv = *thrp;

#pragma unroll 1
  for (int it = 1; it <= NITER; ++it) {
    // ---- GEMM1: u = d @ E^T + c ; s = soft_thr(u) -> bufB ----
#pragma unroll
    for (int rt = 0; rt < 4; ++rt) acc[rt][0] = acc[rt][1] = (floatx4){0.f, 0.f, 0.f, 0.f};
    gemmK512T(bufA, Ef);
#pragma unroll
    for (int rt = 0; rt < 4; ++rt)
#pragma unroll
      for (int ct = 0; ct < 2; ++ct) {
        half4 h;
#pragma unroll
        for (int r = 0; r < 4; ++r) {
          float u = acc[rt][ct][r] + (float)ch[rt][ct][r];
          float s = fmaxf(u - thrv, 0.f) - fmaxf(-u - thrv, 0.f);
          h[r] = (_Float16)s;
        }
        *reinterpret_cast<half4*>(&bufB[(rt * 16 + m16) * LDP + colBase + ct * 16 + q * 4]) = h;
      }
    __syncthreads();

    // ---- GEMM2: d' = s @ D -> bufA (f16) + out slice (fp32, direct) ----
#pragma unroll
    for (int rt = 0; rt < 4; ++rt) acc[rt][0] = acc[rt][1] = (floatx4){0.f, 0.f, 0.f, 0.f};
    gemmK512T(bufB, Dtf);
    float* oslice = out + ((size_t)it * B_SZ + rowBase) * N_SZ;
#pragma unroll
    for (int rt = 0; rt < 4; ++rt)
#pragma unroll
      for (int ct = 0; ct < 2; ++ct) {
        half4 h;
        float4 f;
#pragma unroll
        for (int r = 0; r < 4; ++r) {
          float v = acc[rt][ct][r];
          h[r] = (_Float16)v;
          reinterpret_cast<float*>(&f)[r] = v;
        }
        *reinterpret_cast<half4*>(&bufA[(rt * 16 + m16) * LDP + colBase + ct * 16 + q * 4]) = h;
        *reinterpret_cast<float4*>(oslice + (size_t)(rt * 16 + m16) * N_SZ + colBase + ct * 16 + q * 4) = f;
      }
    __syncthreads();
  }
}

extern "C" void kernel_launch(void* const* d_in, const int* in_sizes, int n_in,
                              void* d_out, int out_size, void* d_ws, size_t ws_size,
                              hipStream_t stream) {
  const float* y = (const float*)d_in[0];
  const float* S = (const float*)d_in[1];
  const float* W = (const float*)d_in[2];
  const float* D = (const float*)d_in[3];
  const float* thr = (const float*)d_in[4];
  float* out = (float*)d_out;

  char* ws = (char*)d_ws;
  _Float16* Ef = (_Float16*)(ws);                    // 512 KB
  _Float16* Df = (_Float16*)(ws + 512 * 1024);       // 512 KB
  _Float16* Dtf = (_Float16*)(ws + 1024 * 1024);     // 512 KB
  _Float16* Wf = (_Float16*)(ws + 1536 * 1024);      // 256 KB
  _Float16* Stf = (_Float16*)(ws + 1792 * 1024);     // 512 KB

  conv_kernel<<<(N_SZ * N_SZ + 255) / 256, 256, 0, stream>>>(S, W, D, Wf, Df, Dtf, Stf);
  ecomp_kernel<<<32, 256, 0, stream>>>(Df, Stf, Ef);
  ista_kernel<<<B_SZ / TB, THREADS, 0, stream>>>(y, Ef, Df, Dtf, Wf, thr, out);
}